// Round 11
// baseline (68.426 us; speedup 1.0000x reference)
//
#include <hip/hip_runtime.h>

#define TOKENS 16384
#define KDIM   2048
#define NEXP   64
#define TOPK   6
#define NSTEPS (KDIM / 32)        // 64 global K-steps

typedef short short8 __attribute__((ext_vector_type(8)));   // 8 bf16 = 4 VGPR
typedef float f32x4  __attribute__((ext_vector_type(4)));

// Exact 3-way truncation split: f == bf(h) + bf(l) + bf(l2) + eps, |eps| <= 2^-24 |f|.
__device__ __forceinline__ void split3(float f, short& h, short& l, short& l2) {
  const unsigned u = __builtin_bit_cast(unsigned, f);
  h = (short)(u >> 16);
  const float r1 = f - __builtin_bit_cast(float, u & 0xffff0000u);
  const unsigned u1 = __builtin_bit_cast(unsigned, r1);
  l = (short)(u1 >> 16);
  const float r2 = r1 - __builtin_bit_cast(float, u1 & 0xffff0000u);
  l2 = (short)(__builtin_bit_cast(unsigned, r2) >> 16);
}

// Kernel 0: pack W into MFMA-B-fragment order, 3-term bf16 split.
// w*[s][nt][lane][j] = term of W[s*32 + (lane>>4)*8 + j][nt*16 + (lane&15)]
__global__ __launch_bounds__(256)
void moe_wpack(const float* __restrict__ wg, short* __restrict__ wh,
               short* __restrict__ wl, short* __restrict__ wl2) {
  const int tid = blockIdx.x * 256 + threadIdx.x;  // 0..16383 = (s, nt, lane)
  const int l  = tid & 63;
  const int nt = (tid >> 6) & 3;
  const int s  = tid >> 8;
  short8 a, b, c;
#pragma unroll
  for (int j = 0; j < 8; ++j) {
    const int k = s * 32 + (l >> 4) * 8 + j;
    const int n = nt * 16 + (l & 15);
    short xh, xl, xl2;
    split3(wg[(size_t)k * NEXP + n], xh, xl, xl2);
    a[j] = xh; b[j] = xl; c[j] = xl2;
  }
  *(short8*)(wh  + (size_t)tid * 8) = a;
  *(short8*)(wl  + (size_t)tid * 8) = b;
  *(short8*)(wl2 + (size_t)tid * 8) = c;
}

// Kernel 1: fully fused GEMM + softmax + top-k, explicitly software-pipelined.
// Grid 1024 -> 4 blocks/CU = 16 waves/CU; no main-loop barriers, no LDS
// staging, no part[]. Wave wid: expert-half eh (2 tiles), K-half kh (32 steps).
// Main loop = 64 half-steps (h = step*2 + tile): w prefetched 1 half-step
// ahead (named regs, ~350cyc > L2 lat), x prefetched 2 steps ahead (~2000cyc
// > L3/HBM lat). unroll 4 -> all stage indices compile-time, copies coalesce.
__global__ __launch_bounds__(256, 4)
void moe_fused(const float* __restrict__ x, const short* __restrict__ wh,
               const short* __restrict__ wl, const short* __restrict__ wl2,
               float* __restrict__ out) {
  __shared__ float red[2][64][8];   // k-high partials: [eh][lane][tt*4+r], 4 KB
  __shared__ float lg[16][NEXP];    // reduced logits, 4 KB

  const int t    = threadIdx.x;
  const int lane = t & 63;
  const int wid  = t >> 6;
  const int row0 = blockIdx.x * 16;
  const int eh   = wid & 1;        // expert half: tiles nt = eh*2, eh*2+1
  const int kh   = wid >> 1;       // K half
  const int r15  = lane & 15;      // token row within tile
  const int kb   = lane >> 4;      // k-subgroup (8 k each)

  f32x4 accB[2] = {};   // hh term per tile
  f32x4 accS[2] = {};   // correction terms per tile

  const short8* __restrict__ whv  = (const short8*)wh;
  const short8* __restrict__ wlv  = (const short8*)wl;
  const short8* __restrict__ wl2v = (const short8*)wl2;

  const float* xrow = x + (size_t)(row0 + r15) * KDIM + kh * (KDIM / 2) + kb * 8;
  // fi(h) = fbase + ((h>>1)*4 + (h&1))*64 ; h = local step*2 + tile
  const int fbase = (kh * 32 * 4 + eh * 2) * 64 + lane;

  // ---- pipeline prologue: x for steps 0,1; w for half-step 0
  float4 xa0 = *(const float4*)(xrow);
  float4 xb0 = *(const float4*)(xrow + 4);
  float4 xa1 = *(const float4*)(xrow + 32);
  float4 xb1 = *(const float4*)(xrow + 36);
  short8 bh  = whv[fbase];
  short8 bl  = wlv[fbase];
  short8 bl2 = wl2v[fbase];

  short8 ah, al, al2;   // split of current step (computed in even bodies)

#pragma unroll 4
  for (int h = 0; h < 64; ++h) {
    // 1) issue next w (used next half-step)
    const int hn  = (h + 1) & 63;
    const int fin = fbase + (((hn >> 1) << 2) + (hn & 1)) * 64;
    short8 nbh  = whv[fin];
    short8 nbl  = wlv[fin];
    short8 nbl2 = wl2v[fin];

    float4 nxa, nxb;
    if ((h & 1) == 0) {
      // 2) issue x for step +2 (wrapped at the tail: redundant, safe)
      const int cn = ((h >> 1) + 2) & 31;
      nxa = *(const float4*)(xrow + cn * 32);
      nxb = *(const float4*)(xrow + cn * 32 + 4);
    }
    __builtin_amdgcn_sched_barrier(0);   // keep load-issue above compute

    if ((h & 1) == 0) {
      // 3) split current step's x (registers, no wait)
#pragma unroll
      for (int e = 0; e < 4; ++e) {
        short h0, l0, m0, h1, l1, m1;
        split3(((const float*)&xa0)[e], h0, l0, m0);
        split3(((const float*)&xb0)[e], h1, l1, m1);
        ah[e] = h0; al[e] = l0; al2[e] = m0;
        ah[e + 4] = h1; al[e + 4] = l1; al2[e + 4] = m1;
      }
    }

    // 4) MFMA cluster for tile tt = h&1 (compile-time under unroll 4)
    __builtin_amdgcn_s_setprio(1);
    if ((h & 1) == 0) {
      accB[0] = __builtin_amdgcn_mfma_f32_16x16x32_bf16(ah,  bh,  accB[0], 0, 0, 0);
      accS[0] = __builtin_amdgcn_mfma_f32_16x16x32_bf16(al,  bh,  accS[0], 0, 0, 0);
      accS[0] = __builtin_amdgcn_mfma_f32_16x16x32_bf16(ah,  bl,  accS[0], 0, 0, 0);
      accS[0] = __builtin_amdgcn_mfma_f32_16x16x32_bf16(al,  bl,  accS[0], 0, 0, 0);
      accS[0] = __builtin_amdgcn_mfma_f32_16x16x32_bf16(ah,  bl2, accS[0], 0, 0, 0);
      accS[0] = __builtin_amdgcn_mfma_f32_16x16x32_bf16(al2, bh,  accS[0], 0, 0, 0);
    } else {
      accB[1] = __builtin_amdgcn_mfma_f32_16x16x32_bf16(ah,  bh,  accB[1], 0, 0, 0);
      accS[1] = __builtin_amdgcn_mfma_f32_16x16x32_bf16(al,  bh,  accS[1], 0, 0, 0);
      accS[1] = __builtin_amdgcn_mfma_f32_16x16x32_bf16(ah,  bl,  accS[1], 0, 0, 0);
      accS[1] = __builtin_amdgcn_mfma_f32_16x16x32_bf16(al,  bl,  accS[1], 0, 0, 0);
      accS[1] = __builtin_amdgcn_mfma_f32_16x16x32_bf16(ah,  bl2, accS[1], 0, 0, 0);
      accS[1] = __builtin_amdgcn_mfma_f32_16x16x32_bf16(al2, bh,  accS[1], 0, 0, 0);
    }
    __builtin_amdgcn_s_setprio(0);

    // 5) rotate pipeline registers (SSA copies, coalesced by unroll)
    bh = nbh; bl = nbl; bl2 = nbl2;
    if ((h & 1) == 0) { xa0 = xa1; xb0 = xb1; xa1 = nxa; xb1 = nxb; }
  }

  // ---- 2-way k-reduction. D: col=lane&15 (expert in tile), row=(lane>>4)*4+r.
  if (kh == 1) {
#pragma unroll
    for (int tt = 0; tt < 2; ++tt)
#pragma unroll
      for (int r = 0; r < 4; ++r)
        red[eh][lane][tt * 4 + r] = accB[tt][r] + accS[tt][r];
  }
  __syncthreads();
  if (kh == 0) {
#pragma unroll
    for (int tt = 0; tt < 2; ++tt)
#pragma unroll
      for (int r = 0; r < 4; ++r)
        lg[(lane >> 4) * 4 + r][(eh * 2 + tt) * 16 + r15] =
            accB[tt][r] + accS[tt][r] + red[eh][lane][tt * 4 + r];
  }
  __syncthreads();

  // ---- softmax + top-k: 16 lanes per token, 4 experts/lane (proven r0 code)
  const int sub  = lane & 15;
  const int tokL = wid * 4 + (lane >> 4);
  float v[4];
  {
    const float4 p = *(const float4*)(&lg[tokL][sub * 4]);
    v[0] = p.x; v[1] = p.y; v[2] = p.z; v[3] = p.w;
  }

  float m = fmaxf(fmaxf(v[0], v[1]), fmaxf(v[2], v[3]));
#pragma unroll
  for (int off = 1; off < 16; off <<= 1) m = fmaxf(m, __shfl_xor(m, off));
  const float p0 = expf(v[0] - m), p1 = expf(v[1] - m);
  const float p2 = expf(v[2] - m), p3 = expf(v[3] - m);
  float s = p0 + p1 + p2 + p3;
#pragma unroll
  for (int off = 1; off < 16; off <<= 1) s += __shfl_xor(s, off);
  v[0] = p0 / s; v[1] = p1 / s; v[2] = p2 / s; v[3] = p3 / s;

  float resv = 0.f; int resi = 0;
#pragma unroll
  for (int rr = 0; rr < TOPK; ++rr) {
    float bv = v[0]; int bi = sub * 4;
#pragma unroll
    for (int j = 1; j < 4; ++j)
      if (v[j] > bv) { bv = v[j]; bi = sub * 4 + j; }   // strict > : lowest idx on tie
#pragma unroll
    for (int off = 1; off < 16; off <<= 1) {
      const float ov = __shfl_xor(bv, off);
      const int   oi = __shfl_xor(bi, off);
      if (ov > bv || (ov == bv && oi < bi)) { bv = ov; bi = oi; }
    }
    if (sub == rr) { resv = bv; resi = bi; }
    if ((bi >> 2) == sub) v[bi & 3] = -1.f;   // scores > 0, sentinel safe
  }

  if (sub < TOPK) {
    const int tok = row0 + tokL;
    out[(size_t)tok * TOPK + sub] = (float)resi;
    out[(size_t)TOKENS * TOPK + (size_t)tok * TOPK + sub] = resv;
  }
}

extern "C" void kernel_launch(void* const* d_in, const int* in_sizes, int n_in,
                              void* d_out, int out_size, void* d_ws, size_t ws_size,
                              hipStream_t stream) {
  const float* x  = (const float*)d_in[0];
  const float* wg = (const float*)d_in[1];
  float* out = (float*)d_out;

  short* wh  = (short*)d_ws;                        // 3 x 131072 shorts = 768 KB
  short* wl  = wh + (size_t)NSTEPS * 4 * 64 * 8;
  short* wl2 = wl + (size_t)NSTEPS * 4 * 64 * 8;

  moe_wpack<<<dim3(64), dim3(256), 0, stream>>>(wg, wh, wl, wl2);
  moe_fused<<<dim3(TOKENS / 16), dim3(256), 0, stream>>>(x, wh, wl, wl2, out);
}

// Round 12
// 55.417 us; speedup vs baseline: 1.2347x; 1.2347x over previous
//
#include <hip/hip_runtime.h>

#define TOKENS 16384
#define KDIM   2048
#define NEXP   64
#define TOPK   6
#define NSTEPS (KDIM / 32)        // 64 global K-steps
#define BM     128                // tokens per block
#define XSB    (BM * 32)          // floats per x buffer (4096 = 16 KB)

typedef short short8 __attribute__((ext_vector_type(8)));   // 8 bf16 = 4 VGPR
typedef float f32x4  __attribute__((ext_vector_type(4)));

// Exact 3-way truncation split: f == bf(h) + bf(l) + bf(l2) + eps, |eps| <= 2^-24 |f|.
__device__ __forceinline__ void split3(float f, short& h, short& l, short& l2) {
  const unsigned u = __builtin_bit_cast(unsigned, f);
  h = (short)(u >> 16);
  const float r1 = f - __builtin_bit_cast(float, u & 0xffff0000u);
  const unsigned u1 = __builtin_bit_cast(unsigned, r1);
  l = (short)(u1 >> 16);
  const float r2 = r1 - __builtin_bit_cast(float, u1 & 0xffff0000u);
  l2 = (short)(__builtin_bit_cast(unsigned, r2) >> 16);
}

__device__ __forceinline__ void g2l16(const void* g, void* l) {
  __builtin_amdgcn_global_load_lds(
      (const __attribute__((address_space(1))) unsigned*)g,
      (__attribute__((address_space(3))) unsigned*)l, 16, 0, 0);
}

// Kernel 0: pack W into MFMA-B-fragment order, 3-term bf16 split.
// w*[s][nt][lane][j] = term of W[s*32 + (lane>>4)*8 + j][nt*16 + (lane&15)]
__global__ __launch_bounds__(256)
void moe_wpack(const float* __restrict__ wg, short* __restrict__ wh,
               short* __restrict__ wl, short* __restrict__ wl2) {
  const int tid = blockIdx.x * 256 + threadIdx.x;  // 0..16383 = (s, nt, lane)
  const int l  = tid & 63;
  const int nt = (tid >> 6) & 3;
  const int s  = tid >> 8;
  short8 a, b, c;
#pragma unroll
  for (int j = 0; j < 8; ++j) {
    const int k = s * 32 + (l >> 4) * 8 + j;
    const int n = nt * 16 + (l & 15);
    short xh, xl, xl2;
    split3(wg[(size_t)k * NEXP + n], xh, xl, xl2);
    a[j] = xh; b[j] = xl; c[j] = xl2;
  }
  *(short8*)(wh  + (size_t)tid * 8) = a;
  *(short8*)(wl  + (size_t)tid * 8) = b;
  *(short8*)(wl2 + (size_t)tid * 8) = c;
}

// Kernel 1: split-K MFMA partial GEMM (6-term bf16 split), 2-deep DMA pipeline.
// Grid (128, ns), 512 threads -> 2 blocks/CU = 16 waves/CU. Wave wid =
// (rq = wid>>2: token half, nt = wid&3: expert tile). Triple-buffered x with
// chunks c+1 AND c+2 in flight -> HBM never idles. Per iter: [3 w-loads] ->
// vmcnt(5) (in-order: retires only DMA(c)) -> RAW s_barrier -> stage(c+2) ->
// compute(c). One barrier/iter; stage-after-barrier makes 3 buffers safe.
__global__ __launch_bounds__(512, 4)
void moe_mfma_ks(const float* __restrict__ x, const short* __restrict__ wh,
                 const short* __restrict__ wl, const short* __restrict__ wl2,
                 float* __restrict__ part, int Kc) {
  __shared__ float xs[3 * XSB];   // 48 KB, triple-buffered

  const int t    = threadIdx.x;
  const int lane = t & 63;
  const int wid  = t >> 6;        // 0..7
  const int nt   = wid & 3;       // expert tile: experts nt*16..+15
  const int rq   = wid >> 2;      // token half: rows rq*64..+63
  const int row0 = blockIdx.x * BM;
  const int k0   = blockIdx.y * Kc;
  const int nch  = Kc >> 5;
  const int s0   = k0 >> 5;       // first global K-step index

  auto stage = [&](int b, int c) {
    // 1024 granules (16B): G = (tok, slot); src granule = slot ^ (tok&7)
#pragma unroll
    for (int j = 0; j < 2; ++j) {
      const int G = j * 512 + t;
      const int tok = G >> 3, slot = G & 7;
      g2l16(x + (size_t)(row0 + tok) * KDIM + k0 + c * 32 + ((slot ^ (tok & 7)) << 2),
            xs + (size_t)b * XSB + (size_t)G * 4);
    }
  };

  f32x4 accB[4] = {};   // hh term, one per local row-group (magnitude ~1)
  f32x4 accS[4] = {};   // correction terms (magnitude ~2^-8)
  const int r15 = lane & 15;
  const int kb  = lane >> 4;      // my k-group of 8
  const int sw  = r15 & 7;        // swizzle key

  const short8* __restrict__ whv  = (const short8*)wh;
  const short8* __restrict__ wlv  = (const short8*)wl;
  const short8* __restrict__ wl2v = (const short8*)wl2;

  stage(0, 0);
  stage(1, 1);                    // 2-deep prologue

  int bc = 0;                     // buffer holding chunk c
  for (int c = 0; c < nch; ++c) {
    // 1) w fragments for MY expert tile (3 loads; shared by 2 waves)
    short8 bh, bl, bl2;
    {
      const int fi = (s0 + c) * 256 + nt * 64 + lane;
      bh  = whv[fi];
      bl  = wlv[fi];
      bl2 = wl2v[fi];
    }
    __builtin_amdgcn_sched_barrier(0);

    // 2) retire only DMA(c). Queue: [DMA(c) 2][DMA(c+1) 2][w 3] -> vmcnt(5);
    //    last iter: [DMA(c) 2][w 3] -> vmcnt(3).
    if (c + 1 < nch) {
      asm volatile("s_waitcnt vmcnt(5)" ::: "memory");
    } else {
      asm volatile("s_waitcnt vmcnt(3)" ::: "memory");
    }
    __builtin_amdgcn_sched_barrier(0);
    __builtin_amdgcn_s_barrier();       // RAW barrier: no vmcnt(0) drain
    __builtin_amdgcn_sched_barrier(0);

    // 3) stage chunk c+2 (buffer (bc+2)%3: its reads finished at iter c-1,
    //    guaranteed by this iter's barrier)
    if (c + 2 < nch) {
      const int b2 = (bc + 2 >= 3) ? bc - 1 : bc + 2;
      stage(b2, c + 2);
    }
    __builtin_amdgcn_sched_barrier(0);

    // 4) compute chunk c from buf bc: 4 row-groups x my 16 experts
#pragma unroll
    for (int rg = 0; rg < 4; ++rg) {
      const float* xrow = xs + (size_t)bc * XSB + (rq * 64 + rg * 16 + r15) * 32;
      const float4 xa = *(const float4*)(xrow + (((kb * 2)     ^ sw) << 2));
      const float4 xb = *(const float4*)(xrow + (((kb * 2 + 1) ^ sw) << 2));
      short8 ah, al, al2;
#pragma unroll
      for (int e = 0; e < 4; ++e) {
        short h0, l0, m0, h1, l1, m1;
        split3(((const float*)&xa)[e], h0, l0, m0);
        split3(((const float*)&xb)[e], h1, l1, m1);
        ah[e] = h0; al[e] = l0; al2[e] = m0;
        ah[e + 4] = h1; al[e + 4] = l1; al2[e + 4] = m1;
      }
      accB[rg] = __builtin_amdgcn_mfma_f32_16x16x32_bf16(ah,  bh,  accB[rg], 0, 0, 0);
      accS[rg] = __builtin_amdgcn_mfma_f32_16x16x32_bf16(al,  bh,  accS[rg], 0, 0, 0);
      accS[rg] = __builtin_amdgcn_mfma_f32_16x16x32_bf16(ah,  bl,  accS[rg], 0, 0, 0);
      accS[rg] = __builtin_amdgcn_mfma_f32_16x16x32_bf16(al,  bl,  accS[rg], 0, 0, 0);
      accS[rg] = __builtin_amdgcn_mfma_f32_16x16x32_bf16(ah,  bl2, accS[rg], 0, 0, 0);
      accS[rg] = __builtin_amdgcn_mfma_f32_16x16x32_bf16(al2, bh,  accS[rg], 0, 0, 0);
    }
    bc = (bc + 1 >= 3) ? 0 : bc + 1;
  }

  // ---- write f32 partials. D: col=lane&15 (expert in my tile),
  // row=(lane>>4)*4+reg (token within row-group).
  float* pb = part + (size_t)blockIdx.y * TOKENS * NEXP;
#pragma unroll
  for (int rg = 0; rg < 4; ++rg)
#pragma unroll
    for (int r = 0; r < 4; ++r)
      pb[(size_t)(row0 + rq * 64 + rg * 16 + kb * 4 + r) * NEXP + nt * 16 + r15] =
          accB[rg][r] + accS[rg][r];
}

// Kernel 2: 16 lanes per token, 4 experts/lane (float4 loads).
// Butterfly reductions within 16-lane groups; 6 argmax rounds with jax
// tie-break (equal score -> lower index). out: indices then scores.
__global__ __launch_bounds__(256)
void moe_softmax_topk(const float* __restrict__ part, float* __restrict__ out, int ns) {
  const int lane = threadIdx.x & 63;
  const int wid  = threadIdx.x >> 6;
  const int sub  = lane & 15;
  const int tok  = blockIdx.x * 16 + wid * 4 + (lane >> 4);

  float v[4] = {0.f, 0.f, 0.f, 0.f};
  for (int ks = 0; ks < ns; ++ks) {
    const float4 p = *(const float4*)(part + ((size_t)ks * TOKENS + tok) * NEXP + sub * 4);
    v[0] += p.x; v[1] += p.y; v[2] += p.z; v[3] += p.w;
  }

  float m = fmaxf(fmaxf(v[0], v[1]), fmaxf(v[2], v[3]));
#pragma unroll
  for (int off = 1; off < 16; off <<= 1) m = fmaxf(m, __shfl_xor(m, off));
  float p0 = expf(v[0] - m), p1 = expf(v[1] - m), p2 = expf(v[2] - m), p3 = expf(v[3] - m);
  float s = p0 + p1 + p2 + p3;
#pragma unroll
  for (int off = 1; off < 16; off <<= 1) s += __shfl_xor(s, off);
  v[0] = p0 / s; v[1] = p1 / s; v[2] = p2 / s; v[3] = p3 / s;

  float resv = 0.f; int resi = 0;
#pragma unroll
  for (int rr = 0; rr < TOPK; ++rr) {
    float bv = v[0]; int bi = sub * 4;
#pragma unroll
    for (int j = 1; j < 4; ++j)
      if (v[j] > bv) { bv = v[j]; bi = sub * 4 + j; }   // strict > : lowest idx on tie
#pragma unroll
    for (int off = 1; off < 16; off <<= 1) {
      const float ov = __shfl_xor(bv, off);
      const int   oi = __shfl_xor(bi, off);
      if (ov > bv || (ov == bv && oi < bi)) { bv = ov; bi = oi; }
    }
    if (sub == rr) { resv = bv; resi = bi; }
    if ((bi >> 2) == sub) v[bi & 3] = -1.f;   // scores > 0, sentinel safe
  }

  if (sub < TOPK) {
    out[(size_t)tok * TOPK + sub] = (float)resi;
    out[(size_t)TOKENS * TOPK + (size_t)tok * TOPK + sub] = resv;
  }
}

extern "C" void kernel_launch(void* const* d_in, const int* in_sizes, int n_in,
                              void* d_out, int out_size, void* d_ws, size_t ws_size,
                              hipStream_t stream) {
  const float* x  = (const float*)d_in[0];
  const float* wg = (const float*)d_in[1];
  float* out = (float*)d_out;

  short* wh  = (short*)d_ws;                        // 3 x 131072 shorts = 768 KB
  short* wl  = wh + (size_t)NSTEPS * 4 * 64 * 8;
  short* wl2 = wl + (size_t)NSTEPS * 4 * 64 * 8;
  const size_t wbytes = (size_t)3 * NSTEPS * 4 * 64 * 8 * sizeof(short);
  float* part = (float*)((char*)d_ws + wbytes);

  int ns = 4;
  while (ns > 1 && wbytes + (size_t)ns * TOKENS * NEXP * sizeof(float) > ws_size) ns >>= 1;
  const int Kc = KDIM / ns;

  moe_wpack<<<dim3(64), dim3(256), 0, stream>>>(wg, wh, wl, wl2);
  moe_mfma_ks<<<dim3(TOKENS / BM, ns), dim3(512), 0, stream>>>(x, wh, wl, wl2, part, Kc);
  moe_softmax_topk<<<dim3(TOKENS / 16), dim3(256), 0, stream>>>(part, out, ns);
}

// Round 13
// 54.732 us; speedup vs baseline: 1.2502x; 1.0125x over previous
//
#include <hip/hip_runtime.h>

#define TOKENS 16384
#define KDIM   2048
#define NEXP   64
#define TOPK   6
#define NSTEPS (KDIM / 32)        // 64 global 32k-steps
#define BM     64                 // tokens per block
#define BK     64                 // k per staged chunk
#define XSB    (BM * BK)          // floats per x buffer (4096 = 16 KB)

typedef short short8 __attribute__((ext_vector_type(8)));   // 8 bf16 = 4 VGPR
typedef float f32x4  __attribute__((ext_vector_type(4)));

// Exact 3-way truncation split: f == bf(h) + bf(l) + bf(l2) + eps, |eps| <= 2^-24 |f|.
__device__ __forceinline__ void split3(float f, short& h, short& l, short& l2) {
  const unsigned u = __builtin_bit_cast(unsigned, f);
  h = (short)(u >> 16);
  const float r1 = f - __builtin_bit_cast(float, u & 0xffff0000u);
  const unsigned u1 = __builtin_bit_cast(unsigned, r1);
  l = (short)(u1 >> 16);
  const float r2 = r1 - __builtin_bit_cast(float, u1 & 0xffff0000u);
  l2 = (short)(__builtin_bit_cast(unsigned, r2) >> 16);
}

__device__ __forceinline__ void g2l16(const void* g, void* l) {
  __builtin_amdgcn_global_load_lds(
      (const __attribute__((address_space(1))) unsigned*)g,
      (__attribute__((address_space(3))) unsigned*)l, 16, 0, 0);
}

// Kernel 0: pack W into MFMA-B-fragment order, 3-term bf16 split.
// w*[s][nt][lane][j] = term of W[s*32 + (lane>>4)*8 + j][nt*16 + (lane&15)]
__global__ __launch_bounds__(256)
void moe_wpack(const float* __restrict__ wg, short* __restrict__ wh,
               short* __restrict__ wl, short* __restrict__ wl2) {
  const int tid = blockIdx.x * 256 + threadIdx.x;  // 0..16383 = (s, nt, lane)
  const int l  = tid & 63;
  const int nt = (tid >> 6) & 3;
  const int s  = tid >> 8;
  short8 a, b, c;
#pragma unroll
  for (int j = 0; j < 8; ++j) {
    const int k = s * 32 + (l >> 4) * 8 + j;
    const int n = nt * 16 + (l & 15);
    short xh, xl, xl2;
    split3(wg[(size_t)k * NEXP + n], xh, xl, xl2);
    a[j] = xh; b[j] = xl; c[j] = xl2;
  }
  *(short8*)(wh  + (size_t)tid * 8) = a;
  *(short8*)(wl  + (size_t)tid * 8) = b;
  *(short8*)(wl2 + (size_t)tid * 8) = c;
}

// Kernel 1: split-K MFMA partial GEMM (6-term bf16 split), BK=64 staging for
// 256B-per-row HBM requests (2x the r7 granularity -> DRAM efficiency).
// Grid (256, ns), 256 thr -> 4 blocks/CU = 16 waves/CU. Wave wid = expert
// tile nt (16 experts) x all 64 tokens. Double-buffered xs; per iter:
// [6 w-loads] -> vmcnt(6) (retires exactly DMA(c)) -> RAW s_barrier ->
// stage(c+1) into other buf (safe: barrier proves its old chunk was consumed)
// -> compute (w-use waits vmcnt(4): DMA(c+1) stays in flight).
__global__ __launch_bounds__(256, 4)
void moe_mfma_ks(const float* __restrict__ x, const short* __restrict__ wh,
                 const short* __restrict__ wl, const short* __restrict__ wl2,
                 float* __restrict__ part, int Kc) {
  __shared__ float xs[2 * XSB];   // 32 KB, double-buffered

  const int t    = threadIdx.x;
  const int lane = t & 63;
  const int nt   = t >> 6;        // wave = expert tile: experts nt*16..+15
  const int row0 = blockIdx.x * BM;
  const int k0   = blockIdx.y * Kc;
  const int nch  = Kc / BK;
  const int s0   = k0 >> 5;       // first global 32k-step index

  // staging: 1024 granules (16B). S = (row T, slot Gp); source granule
  // G = (Gp&8) | ((Gp^T)&7)  (XOR low 3 bits; involution). LDS dest linear.
  auto stage = [&](int b, int c) {
#pragma unroll
    for (int j = 0; j < 4; ++j) {
      const int S = j * 256 + t;
      const int T = S >> 4, Gp = S & 15;
      const int G = (Gp & 8) | ((Gp ^ T) & 7);
      g2l16(x + (size_t)(row0 + T) * KDIM + k0 + c * BK + G * 4,
            xs + (size_t)b * XSB + (size_t)S * 4);
    }
  };

  f32x4 accB[4] = {};   // hh term, one per row-group (magnitude ~1)
  f32x4 accS[4] = {};   // correction terms (magnitude ~2^-8)
  const int r15 = lane & 15;
  const int kb  = lane >> 4;      // my k-group of 8

  const short8* __restrict__ whv  = (const short8*)wh;
  const short8* __restrict__ wlv  = (const short8*)wl;
  const short8* __restrict__ wl2v = (const short8*)wl2;

  stage(0, 0);

  for (int c = 0; c < nch; ++c) {
    const int b = c & 1;
    // 1) w fragments for MY expert tile, both 32k-steps of this chunk
    const int fiA = (s0 + 2 * c) * 256 + nt * 64 + lane;
    const short8 bh0 = whv[fiA],       bl0 = wlv[fiA],       bl20 = wl2v[fiA];
    const short8 bh1 = whv[fiA + 256], bl1 = wlv[fiA + 256], bl21 = wl2v[fiA + 256];
    __builtin_amdgcn_sched_barrier(0);

    // 2) retire exactly DMA(c): queue = [DMA(c):4][w:6]
    asm volatile("s_waitcnt vmcnt(6)" ::: "memory");
    __builtin_amdgcn_sched_barrier(0);
    __builtin_amdgcn_s_barrier();       // RAW barrier: no vmcnt(0) drain
    __builtin_amdgcn_sched_barrier(0);

    // 3) stage chunk c+1 into the other buffer (its old readers passed the barrier)
    if (c + 1 < nch) stage(b ^ 1, c + 1);
    __builtin_amdgcn_sched_barrier(0);

    // 4) compute chunk c: 2 steps x 4 row-groups x my 16 experts
#pragma unroll
    for (int s = 0; s < 2; ++s) {
      const short8 bh  = s ? bh1  : bh0;
      const short8 bl  = s ? bl1  : bl0;
      const short8 bl2 = s ? bl21 : bl20;
#pragma unroll
      for (int rg = 0; rg < 4; ++rg) {
        const int row = rg * 16 + r15;
        const int Ga  = s * 8 + kb * 2;
        const int Gpa = (Ga & 8) | ((Ga ^ row) & 7);
        const int Gpb = (Ga & 8) | (((Ga + 1) ^ row) & 7);
        const float* xr = xs + (size_t)b * XSB + row * 16 * 4;
        const float4 xa = *(const float4*)(xr + Gpa * 4);
        const float4 xb = *(const float4*)(xr + Gpb * 4);
        short8 ah, al, al2;
#pragma unroll
        for (int e = 0; e < 4; ++e) {
          short h0, l0, m0, h1, l1, m1;
          split3(((const float*)&xa)[e], h0, l0, m0);
          split3(((const float*)&xb)[e], h1, l1, m1);
          ah[e] = h0; al[e] = l0; al2[e] = m0;
          ah[e + 4] = h1; al[e + 4] = l1; al2[e + 4] = m1;
        }
        accB[rg] = __builtin_amdgcn_mfma_f32_16x16x32_bf16(ah,  bh,  accB[rg], 0, 0, 0);
        accS[rg] = __builtin_amdgcn_mfma_f32_16x16x32_bf16(al,  bh,  accS[rg], 0, 0, 0);
        accS[rg] = __builtin_amdgcn_mfma_f32_16x16x32_bf16(ah,  bl,  accS[rg], 0, 0, 0);
        accS[rg] = __builtin_amdgcn_mfma_f32_16x16x32_bf16(al,  bl,  accS[rg], 0, 0, 0);
        accS[rg] = __builtin_amdgcn_mfma_f32_16x16x32_bf16(ah,  bl2, accS[rg], 0, 0, 0);
        accS[rg] = __builtin_amdgcn_mfma_f32_16x16x32_bf16(al2, bh,  accS[rg], 0, 0, 0);
      }
    }
  }

  // ---- write f32 partials. D: col=lane&15 (expert in my tile),
  // row=(lane>>4)*4+reg (token within row-group).
  float* pb = part + (size_t)blockIdx.y * TOKENS * NEXP;
#pragma unroll
  for (int rg = 0; rg < 4; ++rg)
#pragma unroll
    for (int r = 0; r < 4; ++r)
      pb[(size_t)(row0 + rg * 16 + kb * 4 + r) * NEXP + nt * 16 + r15] =
          accB[rg][r] + accS[rg][r];
}

// Kernel 2: 16 lanes per token, 4 experts/lane (float4 loads).
// Butterfly reductions within 16-lane groups; 6 argmax rounds with jax
// tie-break (equal score -> lower index). out: indices then scores.
__global__ __launch_bounds__(256)
void moe_softmax_topk(const float* __restrict__ part, float* __restrict__ out, int ns) {
  const int lane = threadIdx.x & 63;
  const int wid  = threadIdx.x >> 6;
  const int sub  = lane & 15;
  const int tok  = blockIdx.x * 16 + wid * 4 + (lane >> 4);

  float v[4] = {0.f, 0.f, 0.f, 0.f};
  for (int ks = 0; ks < ns; ++ks) {
    const float4 p = *(const float4*)(part + ((size_t)ks * TOKENS + tok) * NEXP + sub * 4);
    v[0] += p.x; v[1] += p.y; v[2] += p.z; v[3] += p.w;
  }

  float m = fmaxf(fmaxf(v[0], v[1]), fmaxf(v[2], v[3]));
#pragma unroll
  for (int off = 1; off < 16; off <<= 1) m = fmaxf(m, __shfl_xor(m, off));
  float p0 = expf(v[0] - m), p1 = expf(v[1] - m), p2 = expf(v[2] - m), p3 = expf(v[3] - m);
  float s = p0 + p1 + p2 + p3;
#pragma unroll
  for (int off = 1; off < 16; off <<= 1) s += __shfl_xor(s, off);
  v[0] = p0 / s; v[1] = p1 / s; v[2] = p2 / s; v[3] = p3 / s;

  float resv = 0.f; int resi = 0;
#pragma unroll
  for (int rr = 0; rr < TOPK; ++rr) {
    float bv = v[0]; int bi = sub * 4;
#pragma unroll
    for (int j = 1; j < 4; ++j)
      if (v[j] > bv) { bv = v[j]; bi = sub * 4 + j; }   // strict > : lowest idx on tie
#pragma unroll
    for (int off = 1; off < 16; off <<= 1) {
      const float ov = __shfl_xor(bv, off);
      const int   oi = __shfl_xor(bi, off);
      if (ov > bv || (ov == bv && oi < bi)) { bv = ov; bi = oi; }
    }
    if (sub == rr) { resv = bv; resi = bi; }
    if ((bi >> 2) == sub) v[bi & 3] = -1.f;   // scores > 0, sentinel safe
  }

  if (sub < TOPK) {
    out[(size_t)tok * TOPK + sub] = (float)resi;
    out[(size_t)TOKENS * TOPK + (size_t)tok * TOPK + sub] = resv;
  }
}

extern "C" void kernel_launch(void* const* d_in, const int* in_sizes, int n_in,
                              void* d_out, int out_size, void* d_ws, size_t ws_size,
                              hipStream_t stream) {
  const float* x  = (const float*)d_in[0];
  const float* wg = (const float*)d_in[1];
  float* out = (float*)d_out;

  short* wh  = (short*)d_ws;                        // 3 x 131072 shorts = 768 KB
  short* wl  = wh + (size_t)NSTEPS * 4 * 64 * 8;
  short* wl2 = wl + (size_t)NSTEPS * 4 * 64 * 8;
  const size_t wbytes = (size_t)3 * NSTEPS * 4 * 64 * 8 * sizeof(short);
  float* part = (float*)((char*)d_ws + wbytes);

  int ns = 4;
  while (ns > 1 && wbytes + (size_t)ns * TOKENS * NEXP * sizeof(float) > ws_size) ns >>= 1;
  const int Kc = KDIM / ns;

  moe_wpack<<<dim3(64), dim3(256), 0, stream>>>(wg, wh, wl, wl2);
  moe_mfma_ks<<<dim3(TOKENS / BM, ns), dim3(256), 0, stream>>>(x, wh, wl, wl2, part, Kc);
  moe_softmax_topk<<<dim3(TOKENS / 16), dim3(256), 0, stream>>>(part, out, ns);
}